// Round 2
// baseline (206.099 us; speedup 1.0000x reference)
//
#include <hip/hip_runtime.h>
#include <cstdint>

#define NB 128
#define NBAT 2            // batches interleaved per wave (ILP to fill latency gaps)
#define NT 1024
#define NC 128
#define NL 128
#define NS 257
#define EPSF 1e-7f
#define LN2F 0.69314718055994530942f
#define NEGL2 -1.442695e30f   // *ln2 ~= -1e30 (reference NEG)

__device__ __forceinline__ float fexp2(float x){ return __builtin_amdgcn_exp2f(x); }
__device__ __forceinline__ float flog2(float x){ return __builtin_amdgcn_logf(x); }

// Wave shift-up-by-1 in the VALU pipe: v_mov_b32_dpp wave_shr:1 (ctrl 0x138),
// bound_ctrl=1 -> lane 0 receives 0. All call sites are lane-0-safe.
__device__ __forceinline__ float shup1(float x){
    int r = __builtin_amdgcn_update_dpp(0, __float_as_int(x), 0x138, 0xf, 0xf, true);
    return __int_as_float(r);
}
__device__ __forceinline__ int shup1i(int x){
    return __builtin_amdgcn_update_dpp(0, x, 0x138, 0xf, 0xf, true);
}

// Async global->LDS DMA, 16 B/lane, wave-uniform LDS base (HW adds lane*16).
__device__ __forceinline__ void dma16(const float* g, float* lds){
    __builtin_amdgcn_global_load_lds((const __attribute__((address_space(1))) void*)g,
                                     (__attribute__((address_space(3))) void*)lds,
                                     16, 0, 0);
}

#define VM_DRAIN() asm volatile("s_waitcnt vmcnt(0)" ::: "memory")

// Use-fence per batch: pins that batch's 12 bank registers here (partial
// lgkmcnt wait for the producing ds_reads; newer fills stay outstanding).
#define FENCE12(S, bi) asm volatile("" \
  : "+v"(S##B[bi][0]),"+v"(S##B[bi][1]),"+v"(S##B[bi][2]),"+v"(S##B[bi][3]), \
    "+v"(S##A[bi][0]),"+v"(S##A[bi][1]),"+v"(S##A[bi][2]),"+v"(S##A[bi][3]), \
    "+v"(S##C[bi][0]),"+v"(S##C[bi][1]),"+v"(S##C[bi][2]),"+v"(S##C[bi][3]))

#define FENCEALL(S) do{ _Pragma("unroll") \
    for (int b_ = 0; b_ < NBAT; ++b_) FENCE12(S, b_); }while(0)

// Fill bank S with group gg's p-values for all batches. Row-pair reads at
// stride NC*4=512B merge into ds_read2_b32 (keeps lgkm windows <= 15).
#define FILLALL(S, gg) do{ _Pragma("unroll") \
  for (int b_ = 0; b_ < NBAT; ++b_){ \
    _Pragma("unroll") \
    for (int r_ = 0; r_ < 4; ++r_) S##B[b_][r_] = lB[b_][((gg)*4 + r_) * NC]; \
    _Pragma("unroll") \
    for (int r_ = 0; r_ < 4; ++r_) S##A[b_][r_] = lA[b_][((gg)*4 + r_) * NC]; \
    _Pragma("unroll") \
    for (int r_ = 0; r_ < 4; ++r_) S##C[b_][r_] = lC[b_][((gg)*4 + r_) * NC]; \
  } }while(0)

// One forward step for batch bi (identical arithmetic to the 1-batch kernel).
#define STEP1(S, bi, gg, rr) do{ \
    float Pb_ = S##B[bi][rr] + EPSF; \
    float Pa_ = S##A[bi][rr] + EPSF; \
    float Pc_ = S##C[bi][rr] + EPSF; \
    float t3_ = skip3[bi] ? m1[bi] : 0.f; \
    float n3_ = Pc_ * ((m3[bi] + m2[bi]) + t3_); \
    float n2_ = Pb_ * (m2[bi] + m1[bi]); \
    float n4_ = Pb_ * (m4[bi] + m3[bi]); \
    float pm1_ = shm3[bi] * f0[bi]; \
    float t1_ = shm3[bi] * fs1[bi]; \
    float n0_ = Pb_ * (m0[bi] + pm1_); \
    float n1_ = Pa_ * ((m1[bi] + m0[bi]) + t1_); \
    const bool commit_ = !freeze || ((k*32 + (gg)*4 + (rr)) < Tn[bi]); \
    if (commit_) { m0[bi]=n0_; m1[bi]=n1_; m2[bi]=n2_; m3[bi]=n3_; m4[bi]=n4_; } \
  }while(0)

// Exact pow2 rescale every 4 steps (r6-validated math), per batch.
#define BOUNDARY(bi) do{ \
    float mx_ = fmaxf(fmaxf(m0[bi], m1[bi]), fmaxf(m2[bi], m3[bi])); \
    if (isl63) mx_ = fmaxf(mx_, m4[bi]); \
    const uint32_t bx_ = __float_as_uint(mx_); \
    const uint32_t eb_ = bx_ >> 23; \
    const float inv_ = __uint_as_float((254u - eb_) << 23); \
    const float ef_  = (float)((int)eb_ - 127); \
    const bool dead_ = (mx_ == 0.f); \
    if (early) { \
        float e1_ = dead_ ? e[bi] : (e[bi] + ef_); \
        float s1_ = shup1(e1_); \
        float e2_ = (dead_ && !isl0) ? s1_ : e1_; \
        float s2_ = shup1(e2_); \
        e[bi] = (dead_ && !isl0) ? s2_ : e2_; \
        float d_ = fminf(fmaxf(s2_ - e[bi], -126.f), 126.f); \
        f0[bi] = isl0 ? 0.f : fexp2(d_); \
    } else { \
        e[bi] = dead_ ? e[bi] : (e[bi] + ef_); \
        float s1_ = shup1(e[bi]); \
        float d_ = fminf(fmaxf(s1_ - e[bi], -126.f), 126.f); \
        f0[bi] = isl0 ? 0.f : fexp2(d_); \
    } \
    fs1[bi] = skip1[bi] ? f0[bi] : 0.f; \
    m0[bi] *= inv_; m1[bi] *= inv_; m2[bi] *= inv_; m3[bi] *= inv_; m4[bi] *= inv_; \
    shm3[bi] = shup1(m3[bi]); \
  }while(0)

// 4 steps, batches interleaved at step granularity (bi is the INNER loop so
// the scheduler fills batch A's dep-latency gaps with batch B's instructions).
#define GROUPALL(S, gg) do{ _Pragma("unroll") \
    for (int r_ = 0; r_ < 4; ++r_){ _Pragma("unroll") \
      for (int b_ = 0; b_ < NBAT; ++b_){ \
        STEP1(S, b_, gg, r_); \
        if (r_ < 3) shm3[b_] = shup1(m3[b_]); } } \
    _Pragma("unroll") \
    for (int b_ = 0; b_ < NBAT; ++b_) BOUNDARY(b_); \
  }while(0)

// One wave handles NBAT batches (independent recurrences -> pure ILP).
// Lane l owns extended states 4l..4l+3 of each batch (lane 63 also 256).
// alpha = m * 2^e, exact pow2 rescale every 4 steps.
__global__ __launch_bounds__(64,1)
void ctc_fwd_kernel(const int* __restrict__ y_true,
                    const float* __restrict__ y_pred,
                    const int* __restrict__ input_len,
                    const int* __restrict__ label_len,
                    float* __restrict__ out)
{
    __shared__ float buf[NBAT][2][32 * NC];   // per-batch 2 x 16 KB double buffer
    __shared__ float lg_alpha[NBAT][NS + 3];

    const int b0   = blockIdx.x * NBAT;
    const int lane = threadIdx.x;
    const bool isl0  = (lane == 0);
    const bool isl63 = (lane == 63);

    const float* base[NBAT];
    int   Tn[NBAT];
    int   y0v[NBAT], y1v[NBAT];
    bool  skip1[NBAT], skip3[NBAT];
    float m0[NBAT], m1[NBAT], m2[NBAT], m3[NBAT], m4[NBAT];
    float e[NBAT], f0[NBAT], fs1[NBAT], shm3[NBAT];
    float s0B[NBAT][4], s0A[NBAT][4], s0C[NBAT][4];
    float s1B[NBAT][4], s1A[NBAT][4], s1C[NBAT][4];

#pragma unroll
    for (int bi = 0; bi < NBAT; ++bi){
        const int b = b0 + bi;
        base[bi] = y_pred + (size_t)b * NT * NC;
        int t = input_len[b];
        Tn[bi] = t < 0 ? 0 : (t > NT ? NT : t);
        const int* yrow = y_true + b * NL;
        y0v[bi] = yrow[2 * lane]     & (NC - 1);   // label for state 4l+1
        y1v[bi] = yrow[2 * lane + 1] & (NC - 1);   // label for state 4l+3
        const int yp = shup1i(y1v[bi]);            // y[2l-1] (lane0: unused)
        skip1[bi] = (lane > 0) && (y0v[bi] != yp);
        skip3[bi] = (y1v[bi] != y0v[bi]);
        m0[bi] = isl0 ? 1.f : 0.f;
        m1[bi] = m2[bi] = m3[bi] = m4[bi] = 0.f;
        e[bi]  = 0.f;
        f0[bi] = isl0 ? 0.f : 1.f;
        fs1[bi] = skip1[bi] ? f0[bi] : 0.f;
        shm3[bi] = 0.f;
    }

    auto dma_chunk_all = [&](int c){
#pragma unroll
        for (int bi = 0; bi < NBAT; ++bi){
            const float* gsrc = base[bi] + (size_t)c * 32 * NC;
            float* dst = &buf[bi][c & 1][0];
#pragma unroll
            for (int i = 0; i < 16; ++i)
                dma16(gsrc + i * 256 + lane * 4, dst + i * 256);
        }
    };

    auto chunkbody = [&](int k, bool early, bool freeze){
        const int h = k & 1;
        const float* lB[NBAT]; const float* lA[NBAT]; const float* lC[NBAT];
#pragma unroll
        for (int bi = 0; bi < NBAT; ++bi){
            lB[bi] = &buf[bi][h][NC - 1];
            lA[bi] = &buf[bi][h][y0v[bi]];
            lC[bi] = &buf[bi][h][y1v[bi]];
        }
        FILLALL(s0, 0);                       // group 0 (chunk k already drained)
        if (k + 1 < 32) dma_chunk_all(k + 1); // stage next chunk (other half)

        FILLALL(s1, 1); FENCEALL(s0); GROUPALL(s0, 0);
        FILLALL(s0, 2); FENCEALL(s1); GROUPALL(s1, 1);
        FILLALL(s1, 3); FENCEALL(s0); GROUPALL(s0, 2);
        FILLALL(s0, 4); FENCEALL(s1); GROUPALL(s1, 3);
        FILLALL(s1, 5); FENCEALL(s0); GROUPALL(s0, 4);
        FILLALL(s0, 6); FENCEALL(s1); GROUPALL(s1, 5);
        FILLALL(s1, 7); FENCEALL(s0); GROUPALL(s0, 6);
                        FENCEALL(s1); GROUPALL(s1, 7);

        VM_DRAIN();   // next chunk's DMA complete; barrier for the compiler too
    };

    // prologue: stage chunk 0 for all batches, drain
    dma_chunk_all(0);
    VM_DRAIN();

    // Tn in [512,1024]: chunks 0..15 fully active; freeze checked for k>=16
#pragma unroll 1
    for (int k = 0; k < 8; ++k)   chunkbody(k, true,  false);
#pragma unroll 1
    for (int k = 8; k < 16; ++k)  chunkbody(k, false, false);
#pragma unroll 1
    for (int k = 16; k < 32; ++k) chunkbody(k, false, true);

    // ---- epilogue ----
#pragma unroll
    for (int bi = 0; bi < NBAT; ++bi){
        lg_alpha[bi][4 * lane + 0] = (m0[bi] > 0.f) ? (e[bi] + flog2(m0[bi])) : NEGL2;
        lg_alpha[bi][4 * lane + 1] = (m1[bi] > 0.f) ? (e[bi] + flog2(m1[bi])) : NEGL2;
        lg_alpha[bi][4 * lane + 2] = (m2[bi] > 0.f) ? (e[bi] + flog2(m2[bi])) : NEGL2;
        lg_alpha[bi][4 * lane + 3] = (m3[bi] > 0.f) ? (e[bi] + flog2(m3[bi])) : NEGL2;
        if (isl63) lg_alpha[bi][256] = (m4[bi] > 0.f) ? (e[bi] + flog2(m4[bi])) : NEGL2;
    }
    __syncthreads();

    if (lane < NBAT) {
        const int bi = lane;
        int lab = label_len[b0 + bi];
        lab = lab < 0 ? 0 : (lab > NL ? NL : lab);
        const int i_last = 2 * lab;
        const int i_prev = i_last > 0 ? i_last - 1 : 0;
        float A  = lg_alpha[bi][i_last];
        float Bv = lg_alpha[bi][i_prev];
        float mx = fmaxf(A, Bv);
        float r;
        if (mx < -1.0e29f) {
            r = mx;
        } else {
            float s = fexp2(A - mx) + fexp2(Bv - mx);
            r = mx + flog2(s);
        }
        out[b0 + bi] = -r * LN2F;
    }
}

extern "C" void kernel_launch(void* const* d_in, const int* in_sizes, int n_in,
                              void* d_out, int out_size, void* d_ws, size_t ws_size,
                              hipStream_t stream) {
    const int*   y_true    = (const int*)d_in[0];
    const float* y_pred    = (const float*)d_in[1];
    const int*   input_len = (const int*)d_in[2];
    const int*   label_len = (const int*)d_in[3];
    float* outp = (float*)d_out;
    ctc_fwd_kernel<<<dim3(NB / NBAT), dim3(64), 0, stream>>>(y_true, y_pred, input_len, label_len, outp);
}

// Round 3
// 156.226 us; speedup vs baseline: 1.3192x; 1.3192x over previous
//
#include <hip/hip_runtime.h>
#include <cstdint>

#define NB 128
#define NT 1024
#define NC 128
#define NL 128
#define NS 257
#define EPSF 1e-7f
#define LN2F 0.69314718055994530942f
#define NEGL2 -1.442695e30f   // *ln2 ~= -1e30 (reference NEG)

__device__ __forceinline__ float fexp2(float x){ return __builtin_amdgcn_exp2f(x); }
__device__ __forceinline__ float flog2(float x){ return __builtin_amdgcn_logf(x); }

// Wave shift-up-by-1 in the VALU pipe: v_mov_b32_dpp wave_shr:1 (ctrl 0x138),
// bound_ctrl=1 -> lane 0 receives 0. All call sites are lane-0-safe.
__device__ __forceinline__ float shup1(float x){
    int r = __builtin_amdgcn_update_dpp(0, __float_as_int(x), 0x138, 0xf, 0xf, true);
    return __int_as_float(r);
}
__device__ __forceinline__ int shup1i(int x){
    return __builtin_amdgcn_update_dpp(0, x, 0x138, 0xf, 0xf, true);
}

// Async global->LDS DMA, 16 B/lane, wave-uniform LDS base (HW adds lane*16).
// Tracked by vmcnt; zero registers; issue cost only — off the serial chain.
__device__ __forceinline__ void dma16(const float* g, float* lds){
    __builtin_amdgcn_global_load_lds((const __attribute__((address_space(1))) void*)g,
                                     (__attribute__((address_space(3))) void*)lds,
                                     16, 0, 0);
}

// HW drain of DMA + compiler-level memory barrier (no load may cross).
#define VM_DRAIN() asm volatile("s_waitcnt vmcnt(0)" ::: "memory")

// Use-fence: forces the named 12 registers to hold their loaded values HERE.
// Pins the producing ds_reads before this point (data dep), makes the
// compiler wait only for them (newer fills stay outstanding), and cannot be
// deleted or crossed by the consumer (reads/writes the same regs).
#define FENCE12(S) asm volatile("" \
  : "+v"(S##B[0]),"+v"(S##B[1]),"+v"(S##B[2]),"+v"(S##B[3]), \
    "+v"(S##A[0]),"+v"(S##A[1]),"+v"(S##A[2]),"+v"(S##A[3]), \
    "+v"(S##C[0]),"+v"(S##C[1]),"+v"(S##C[2]),"+v"(S##C[3]))

// Fill one register bank with group gg's 12 p-values (plain ds_reads).
#define FILL(S, gg) do{ _Pragma("unroll") \
    for (int r_ = 0; r_ < 4; ++r_){ \
        S##B[r_] = lB[((gg)*4 + r_) * NC]; \
        S##A[r_] = lA[((gg)*4 + r_) * NC]; \
        S##C[r_] = lC[((gg)*4 + r_) * NC]; } }while(0)

#define GROUP(S, gg) do{ _Pragma("unroll") \
    for (int r_ = 0; r_ < 4; ++r_){ \
        const bool commit_ = !freeze || ((k*32 + (gg)*4 + r_) < Tn); \
        step1(S##B[r_], S##A[r_], S##C[r_], commit_); \
        if (r_ < 3) shm3 = shup1(m3); } \
    boundary(early); }while(0)

// One wave per batch. Lane l owns extended states 4l..4l+3 (lane 63 also 256).
// alpha = m * 2^e, exact pow2 rescale every 4 steps (r6-validated math).
// Memory plan: 32-row chunks DMA'd to LDS one chunk ahead; LDS->reg prefetch
// TWO 4-step groups ahead (3 rotating banks), pinned by asm use-fences, so
// every fence's producing ds_reads are a full group (~750 cyc) upstream.
__global__ __launch_bounds__(64,1)
void ctc_fwd_kernel(const int* __restrict__ y_true,
                    const float* __restrict__ y_pred,
                    const int* __restrict__ input_len,
                    const int* __restrict__ label_len,
                    float* __restrict__ out)
{
    __shared__ float buf[2][32 * NC];   // 2 x 16 KB double-buffered prob rows
    __shared__ float lg_alpha[NS + 3];

    const int b    = blockIdx.x;
    const int lane = threadIdx.x;
    const float* __restrict__ base = y_pred + (size_t)b * NT * NC;

    int Tn = input_len[b];
    Tn = Tn < 0 ? 0 : (Tn > NT ? NT : Tn);   // setup guarantees Tn in [512,1024]

    const int* __restrict__ yrow = y_true + b * NL;
    const int y0v = yrow[2 * lane]     & (NC - 1);   // label for state 4l+1
    const int y1v = yrow[2 * lane + 1] & (NC - 1);   // label for state 4l+3
    const int yp  = shup1i(y1v);                     // y[2l-1] (lane0: unused)
    const bool skip1 = (lane > 0) && (y0v != yp);
    const bool skip3 = (y1v != y0v);
    const bool isl0  = (lane == 0);
    const bool isl63 = (lane == 63);

    float m0 = isl0 ? 1.f : 0.f, m1 = 0.f, m2 = 0.f, m3 = 0.f, m4 = 0.f;
    float e   = 0.f;              // per-lane log2 scale (integer-valued, exact)
    float f0  = isl0 ? 0.f : 1.f; // neighbor->self scale factor (per group)
    float fs1 = skip1 ? f0 : 0.f;
    float shm3 = 0.f;             // neighbor's m3 (prev step), own scale

    // three rotating register banks: one 4-step group of p-values each
    float s0B[4], s0A[4], s0C[4];
    float s1B[4], s1A[4], s1C[4];
    float s2B[4], s2A[4], s2C[4];

    auto dma_chunk = [&](int c){              // stage chunk c into buf[c&1]
        const float* gsrc = base + (size_t)c * 32 * NC;
        float* dst = &buf[c & 1][0];
        #pragma unroll
        for (int i = 0; i < 16; ++i)
            dma16(gsrc + i * 256 + lane * 4, dst + i * 256);
    };

    auto step1 = [&](float Pb, float Pa, float Pc, bool commit){
        Pb += EPSF; Pa += EPSF; Pc += EPSF;
        float t3  = skip3 ? m1 : 0.f;
        float n3  = Pc * ((m3 + m2) + t3);
        float n2  = Pb * (m2 + m1);
        float n4  = Pb * (m4 + m3);
        float pm1 = shm3 * f0;                 // alpha[4l-1] in own scale
        float t1  = shm3 * fs1;
        float n0  = Pb * (m0 + pm1);
        float n1  = Pa * ((m1 + m0) + t1);
        if (commit) { m0 = n0; m1 = n1; m2 = n2; m3 = n3; m4 = n4; }
    };

    auto boundary = [&](bool early){
        float mx = fmaxf(fmaxf(m0, m1), fmaxf(m2, m3));
        if (isl63) mx = fmaxf(mx, m4);
        const uint32_t bx = __float_as_uint(mx);
        const uint32_t eb = bx >> 23;
        const float inv = __uint_as_float((254u - eb) << 23);  // exact 2^-ef
        const float ef  = (float)((int)eb - 127);
        const bool dead = (mx == 0.f);
        if (early) {
            // two-pass scale adoption while the reachability front propagates
            float e1 = dead ? e : (e + ef);
            float s1 = shup1(e1);
            float e2 = (dead && !isl0) ? s1 : e1;
            float s2 = shup1(e2);
            e = (dead && !isl0) ? s2 : e2;
            float d = fminf(fmaxf(s2 - e, -126.f), 126.f);
            f0 = isl0 ? 0.f : fexp2(d);
        } else {
            e = dead ? e : (e + ef);
            float s1 = shup1(e);
            float d = fminf(fmaxf(s1 - e, -126.f), 126.f);
            f0 = isl0 ? 0.f : fexp2(d);
        }
        fs1 = skip1 ? f0 : 0.f;
        m0 *= inv; m1 *= inv; m2 *= inv; m3 *= inv; m4 *= inv;
        shm3 = shup1(m3);                      // post-rescale, matches new f0
    };

    auto chunkbody = [&](int k, bool early, bool freeze){
        const int h = k & 1;
        const float* lB = &buf[h][NC - 1];
        const float* lA = &buf[h][y0v];
        const float* lC = &buf[h][y1v];

        FILL(s0, 0);                      // group 0 (chunk k already drained)
        if (k + 1 < 32) dma_chunk(k + 1); // stage next chunk (other half)
        FILL(s1, 1);                      // group 1 — 2-deep from the start

        FILL(s2, 2); FENCE12(s0); GROUP(s0, 0);
        FILL(s0, 3); FENCE12(s1); GROUP(s1, 1);
        FILL(s1, 4); FENCE12(s2); GROUP(s2, 2);
        FILL(s2, 5); FENCE12(s0); GROUP(s0, 3);
        FILL(s0, 6); FENCE12(s1); GROUP(s1, 4);
        FILL(s1, 7); FENCE12(s2); GROUP(s2, 5);
                     FENCE12(s0); GROUP(s0, 6);
                     FENCE12(s1); GROUP(s1, 7);

        VM_DRAIN();   // next chunk's DMA complete; barrier for the compiler too
    };

    // prologue: stage chunk 0, drain
    dma_chunk(0);
    VM_DRAIN();

    // Tn in [512,1024]: chunks 0..15 fully active; freeze checked for k>=16
    #pragma unroll 1
    for (int k = 0; k < 8; ++k)   chunkbody(k, true,  false);
    #pragma unroll 1
    for (int k = 8; k < 16; ++k)  chunkbody(k, false, false);
    #pragma unroll 1
    for (int k = 16; k < 32; ++k) chunkbody(k, false, true);

    // ---- epilogue ----
    lg_alpha[4 * lane + 0] = (m0 > 0.f) ? (e + flog2(m0)) : NEGL2;
    lg_alpha[4 * lane + 1] = (m1 > 0.f) ? (e + flog2(m1)) : NEGL2;
    lg_alpha[4 * lane + 2] = (m2 > 0.f) ? (e + flog2(m2)) : NEGL2;
    lg_alpha[4 * lane + 3] = (m3 > 0.f) ? (e + flog2(m3)) : NEGL2;
    if (isl63) lg_alpha[256] = (m4 > 0.f) ? (e + flog2(m4)) : NEGL2;
    __syncthreads();

    if (lane == 0) {
        int lab = label_len[b];
        lab = lab < 0 ? 0 : (lab > NL ? NL : lab);
        const int i_last = 2 * lab;
        const int i_prev = i_last > 0 ? i_last - 1 : 0;
        float A  = lg_alpha[i_last];
        float Bv = lg_alpha[i_prev];
        float mx = fmaxf(A, Bv);
        float r;
        if (mx < -1.0e29f) {
            r = mx;
        } else {
            float s = fexp2(A - mx) + fexp2(Bv - mx);
            r = mx + flog2(s);
        }
        out[b] = -r * LN2F;
    }
}

extern "C" void kernel_launch(void* const* d_in, const int* in_sizes, int n_in,
                              void* d_out, int out_size, void* d_ws, size_t ws_size,
                              hipStream_t stream) {
    const int*   y_true    = (const int*)d_in[0];
    const float* y_pred    = (const float*)d_in[1];
    const int*   input_len = (const int*)d_in[2];
    const int*   label_len = (const int*)d_in[3];
    float* outp = (float*)d_out;
    ctc_fwd_kernel<<<dim3(NB), dim3(64), 0, stream>>>(y_true, y_pred, input_len, label_len, outp);
}

// Round 5
// 147.161 us; speedup vs baseline: 1.4005x; 1.0616x over previous
//
#include <hip/hip_runtime.h>
#include <cstdint>

#define NB 128
#define NT 1024
#define NC 128
#define NL 128
#define NS 257
#define EPSF 1e-7f
#define LN2F 0.69314718055994530942f
#define NEGL2 -1.442695e30f   // *ln2 ~= -1e30 (reference NEG)

typedef float __attribute__((ext_vector_type(2))) v2f;

__device__ __forceinline__ float fexp2(float x){ return __builtin_amdgcn_exp2f(x); }
__device__ __forceinline__ float flog2(float x){ return __builtin_amdgcn_logf(x); }

// Wave shift-up-by-1 in the VALU pipe: v_mov_b32_dpp wave_shr:1 (ctrl 0x138),
// bound_ctrl=1 -> lane 0 receives 0. All call sites are lane-0-safe.
__device__ __forceinline__ float shup1(float x){
    int r = __builtin_amdgcn_update_dpp(0, __float_as_int(x), 0x138, 0xf, 0xf, true);
    return __int_as_float(r);
}
__device__ __forceinline__ int shup1i(int x){
    return __builtin_amdgcn_update_dpp(0, x, 0x138, 0xf, 0xf, true);
}

// Async global->LDS DMA, 16 B/lane, wave-uniform LDS base (HW adds lane*16).
// Tracked by vmcnt; zero registers; issue cost only — off the serial chain.
__device__ __forceinline__ void dma16(const float* g, float* lds){
    __builtin_amdgcn_global_load_lds((const __attribute__((address_space(1))) void*)g,
                                     (__attribute__((address_space(3))) void*)lds,
                                     16, 0, 0);
}

// HW drain of DMA + compiler-level memory barrier (no load may cross).
#define VM_DRAIN() asm volatile("s_waitcnt vmcnt(0)" ::: "memory")

// LDS byte-offset of a __shared__ address (for raw ds_read asm).
#define AS3U(p) ((unsigned)(size_t)(__attribute__((address_space(3))) void*)(p))

// Hand-counted LDS wait + scheduling wall (rule #18: the sched_barrier stops
// the compiler hoisting dependent VALU between the ds_read asm and the wait).
#define WAITLGKM(N) do{ asm volatile("s_waitcnt lgkmcnt(" #N ")" ::: "memory"); \
                        __builtin_amdgcn_sched_barrier(0); }while(0)

// Pinned fill: 6x volatile ds_read2st64_b32 (st64 unit = 256 B; row stride
// 512 B = 2 units). Volatile asm cannot be reordered against other volatile
// asm, so these ISSUE here — two groups ahead of their consumer — and cannot
// be sunk to just-before-use by the scheduler (the round-0..3 suspicion).
// O0..O3 are literal st64 offsets for rows g*4+0..3: (g*4+r)*2.
#define FILLA(S, O0,O1,O2,O3) do{ \
  asm volatile("ds_read2st64_b32 %0, %1 offset0:" #O0 " offset1:" #O1 : "=v"(S##B2[0]) : "v"(aB)); \
  asm volatile("ds_read2st64_b32 %0, %1 offset0:" #O2 " offset1:" #O3 : "=v"(S##B2[1]) : "v"(aB)); \
  asm volatile("ds_read2st64_b32 %0, %1 offset0:" #O0 " offset1:" #O1 : "=v"(S##A2[0]) : "v"(aA)); \
  asm volatile("ds_read2st64_b32 %0, %1 offset0:" #O2 " offset1:" #O3 : "=v"(S##A2[1]) : "v"(aA)); \
  asm volatile("ds_read2st64_b32 %0, %1 offset0:" #O0 " offset1:" #O1 : "=v"(S##C2[0]) : "v"(aC)); \
  asm volatile("ds_read2st64_b32 %0, %1 offset0:" #O2 " offset1:" #O3 : "=v"(S##C2[1]) : "v"(aC)); \
}while(0)

// 4 steps consuming bank S (pairs: S?2[r>>1][r&1] = row g*4+r), then boundary.
#define GROUP(S, gg) do{ _Pragma("unroll") \
    for (int r_ = 0; r_ < 4; ++r_){ \
        const bool commit_ = !freeze || ((k*32 + (gg)*4 + r_) < Tn); \
        step1(S##B2[r_>>1][r_&1], S##A2[r_>>1][r_&1], S##C2[r_>>1][r_&1], commit_); \
        if (r_ < 3) shm3 = shup1(m3); } \
    boundary(early); }while(0)

// One wave per batch. Lane l owns extended states 4l..4l+3 (lane 63 also 256).
// alpha = m * 2^e, exact pow2 rescale every 4 steps (r6-validated math).
// Memory plan: 32-row chunks DMA'd to LDS one chunk ahead; LDS->reg prefetch
// two 4-step groups ahead via PINNED volatile ds_read2st64 + counted lgkmcnt.
__global__ __launch_bounds__(64,1)
void ctc_fwd_kernel(const int* __restrict__ y_true,
                    const float* __restrict__ y_pred,
                    const int* __restrict__ input_len,
                    const int* __restrict__ label_len,
                    float* __restrict__ out)
{
    __shared__ float buf[2][32 * NC];   // 2 x 16 KB double-buffered prob rows
    __shared__ float lg_alpha[NS + 3];

    const int b    = blockIdx.x;
    const int lane = threadIdx.x;
    const float* __restrict__ base = y_pred + (size_t)b * NT * NC;

    int Tn = input_len[b];
    Tn = Tn < 0 ? 0 : (Tn > NT ? NT : Tn);   // setup guarantees Tn in [512,1024]

    const int* __restrict__ yrow = y_true + b * NL;
    const int y0v = yrow[2 * lane]     & (NC - 1);   // label for state 4l+1
    const int y1v = yrow[2 * lane + 1] & (NC - 1);   // label for state 4l+3
    const int yp  = shup1i(y1v);                     // y[2l-1] (lane0: unused)
    const bool skip1 = (lane > 0) && (y0v != yp);
    const bool skip3 = (y1v != y0v);
    const bool isl0  = (lane == 0);
    const bool isl63 = (lane == 63);

    float m0 = isl0 ? 1.f : 0.f, m1 = 0.f, m2 = 0.f, m3 = 0.f, m4 = 0.f;
    float e   = 0.f;              // per-lane log2 scale (integer-valued, exact)
    float f0  = isl0 ? 0.f : 1.f; // neighbor->self scale factor (per group)
    float fs1 = skip1 ? f0 : 0.f;
    float shm3 = 0.f;             // neighbor's m3 (prev step), own scale

    // three rotating register banks: one 4-step group of p-value pairs each
    v2f s0B2[2], s0A2[2], s0C2[2];
    v2f s1B2[2], s1A2[2], s1C2[2];
    v2f s2B2[2], s2A2[2], s2C2[2];

    auto dma_chunk = [&](int c){              // stage chunk c into buf[c&1]
        const float* gsrc = base + (size_t)c * 32 * NC;
        float* dst = &buf[c & 1][0];
        #pragma unroll
        for (int i = 0; i < 16; ++i)
            dma16(gsrc + i * 256 + lane * 4, dst + i * 256);
    };

    auto step1 = [&](float Pb, float Pa, float Pc, bool commit){
        Pb += EPSF; Pa += EPSF; Pc += EPSF;
        float t3  = skip3 ? m1 : 0.f;
        float n3  = Pc * ((m3 + m2) + t3);
        float n2  = Pb * (m2 + m1);
        float n4  = Pb * (m4 + m3);
        float pm1 = shm3 * f0;                 // alpha[4l-1] in own scale
        float t1  = shm3 * fs1;
        float n0  = Pb * (m0 + pm1);
        float n1  = Pa * ((m1 + m0) + t1);
        if (commit) { m0 = n0; m1 = n1; m2 = n2; m3 = n3; m4 = n4; }
    };

    auto boundary = [&](bool early){
        float mx = fmaxf(fmaxf(m0, m1), fmaxf(m2, m3));
        if (isl63) mx = fmaxf(mx, m4);
        const uint32_t bx = __float_as_uint(mx);
        const uint32_t eb = bx >> 23;
        const float inv = __uint_as_float((254u - eb) << 23);  // exact 2^-ef
        const float ef  = (float)((int)eb - 127);
        const bool dead = (mx == 0.f);
        if (early) {
            // two-pass scale adoption while the reachability front propagates
            float e1 = dead ? e : (e + ef);
            float s1 = shup1(e1);
            float e2 = (dead && !isl0) ? s1 : e1;
            float s2 = shup1(e2);
            e = (dead && !isl0) ? s2 : e2;
            float d = fminf(fmaxf(s2 - e, -126.f), 126.f);
            f0 = isl0 ? 0.f : fexp2(d);
        } else {
            e = dead ? e : (e + ef);
            float s1 = shup1(e);
            float d = fminf(fmaxf(s1 - e, -126.f), 126.f);
            f0 = isl0 ? 0.f : fexp2(d);
        }
        fs1 = skip1 ? f0 : 0.f;
        m0 *= inv; m1 *= inv; m2 *= inv; m3 *= inv; m4 *= inv;
        shm3 = shup1(m3);                      // post-rescale, matches new f0
    };

    auto chunkbody = [&](int k, bool early, bool freeze){
        const int h = k & 1;
        const unsigned aB = AS3U(&buf[h][NC - 1]);   // blank prob (uniform addr)
        const unsigned aA = AS3U(&buf[h][y0v]);      // label prob, state 4l+1
        const unsigned aC = AS3U(&buf[h][y1v]);      // label prob, state 4l+3

        FILLA(s0,  0, 2, 4, 6);           // group 0 (chunk k already drained)
        if (k + 1 < 32) dma_chunk(k + 1); // stage next chunk (other half)
        FILLA(s1,  8,10,12,14);           // group 1 — 2-deep from the start

        // steady state: every use waits only past the 2 newer in-flight fills
        FILLA(s2, 16,18,20,22); WAITLGKM(12); GROUP(s0, 0);
        FILLA(s0, 24,26,28,30); WAITLGKM(12); GROUP(s1, 1);
        FILLA(s1, 32,34,36,38); WAITLGKM(12); GROUP(s2, 2);
        FILLA(s2, 40,42,44,46); WAITLGKM(12); GROUP(s0, 3);
        FILLA(s0, 48,50,52,54); WAITLGKM(12); GROUP(s1, 4);
        FILLA(s1, 56,58,60,62); WAITLGKM(12); GROUP(s2, 5);
                                WAITLGKM(6);  GROUP(s0, 6);
                                WAITLGKM(0);  GROUP(s1, 7);

        VM_DRAIN();   // next chunk's DMA complete; barrier for the compiler too
    };

    // prologue: stage chunk 0, drain
    dma_chunk(0);
    VM_DRAIN();

    // Tn in [512,1024]: chunks 0..15 fully active; freeze checked for k>=16
    #pragma unroll 1
    for (int k = 0; k < 8; ++k)   chunkbody(k, true,  false);
    #pragma unroll 1
    for (int k = 8; k < 16; ++k)  chunkbody(k, false, false);
    #pragma unroll 1
    for (int k = 16; k < 32; ++k) chunkbody(k, false, true);

    // ---- epilogue ----
    lg_alpha[4 * lane + 0] = (m0 > 0.f) ? (e + flog2(m0)) : NEGL2;
    lg_alpha[4 * lane + 1] = (m1 > 0.f) ? (e + flog2(m1)) : NEGL2;
    lg_alpha[4 * lane + 2] = (m2 > 0.f) ? (e + flog2(m2)) : NEGL2;
    lg_alpha[4 * lane + 3] = (m3 > 0.f) ? (e + flog2(m3)) : NEGL2;
    if (isl63) lg_alpha[256] = (m4 > 0.f) ? (e + flog2(m4)) : NEGL2;
    __syncthreads();

    if (lane == 0) {
        int lab = label_len[b];
        lab = lab < 0 ? 0 : (lab > NL ? NL : lab);
        const int i_last = 2 * lab;
        const int i_prev = i_last > 0 ? i_last - 1 : 0;
        float A  = lg_alpha[i_last];
        float Bv = lg_alpha[i_prev];
        float mx = fmaxf(A, Bv);
        float r;
        if (mx < -1.0e29f) {
            r = mx;
        } else {
            float s = fexp2(A - mx) + fexp2(Bv - mx);
            r = mx + flog2(s);
        }
        out[b] = -r * LN2F;
    }
}

extern "C" void kernel_launch(void* const* d_in, const int* in_sizes, int n_in,
                              void* d_out, int out_size, void* d_ws, size_t ws_size,
                              hipStream_t stream) {
    const int*   y_true    = (const int*)d_in[0];
    const float* y_pred    = (const float*)d_in[1];
    const int*   input_len = (const int*)d_in[2];
    const int*   label_len = (const int*)d_in[3];
    float* outp = (float*)d_out;
    ctc_fwd_kernel<<<dim3(NB), dim3(64), 0, stream>>>(y_true, y_pred, input_len, label_len, outp);
}

// Round 6
// 145.060 us; speedup vs baseline: 1.4208x; 1.0145x over previous
//
#include <hip/hip_runtime.h>
#include <cstdint>

#define NB 128
#define NT 1024
#define NC 128
#define NL 128
#define NS 257
#define EPSF 1e-7f
#define LN2F 0.69314718055994530942f
#define NEGL2 -1.442695e30f   // *ln2 ~= -1e30 (reference NEG)

typedef float __attribute__((ext_vector_type(2))) v2f;

__device__ __forceinline__ float fexp2(float x){ return __builtin_amdgcn_exp2f(x); }
__device__ __forceinline__ float flog2(float x){ return __builtin_amdgcn_logf(x); }

// Wave shift-up-by-1 in the VALU pipe: v_mov_b32_dpp wave_shr:1 (ctrl 0x138),
// bound_ctrl=1 -> lane 0 receives 0. All call sites are lane-0-safe.
__device__ __forceinline__ float shup1(float x){
    int r = __builtin_amdgcn_update_dpp(0, __float_as_int(x), 0x138, 0xf, 0xf, true);
    return __int_as_float(r);
}
__device__ __forceinline__ int shup1i(int x){
    return __builtin_amdgcn_update_dpp(0, x, 0x138, 0xf, 0xf, true);
}

// Async global->LDS DMA, 16 B/lane, wave-uniform LDS base (HW adds lane*16).
// Tracked by vmcnt; zero registers; issue cost only — off the serial chain.
__device__ __forceinline__ void dma16(const float* g, float* lds){
    __builtin_amdgcn_global_load_lds((const __attribute__((address_space(1))) void*)g,
                                     (__attribute__((address_space(3))) void*)lds,
                                     16, 0, 0);
}

// HW drain of DMA + compiler-level memory barrier (no load may cross).
#define VM_DRAIN() asm volatile("s_waitcnt vmcnt(0)" ::: "memory")

// LDS byte-offset of a __shared__ address (for raw ds_read asm).
#define AS3U(p) ((unsigned)(size_t)(__attribute__((address_space(3))) void*)(p))

// Hand-counted LDS wait + scheduling wall (rule #18: the sched_barrier stops
// the compiler hoisting dependent VALU between the ds_read asm and the wait).
#define WAITLGKM(N) do{ asm volatile("s_waitcnt lgkmcnt(" #N ")" ::: "memory"); \
                        __builtin_amdgcn_sched_barrier(0); }while(0)

// Pinned fill: 6x volatile ds_read2st64_b32 (st64 unit = 256 B; row stride
// 512 B = 2 units). Volatile asm cannot be reordered against other volatile
// asm, so these ISSUE here — two groups ahead of their consumer — and cannot
// be sunk to just-before-use by the scheduler (r5-confirmed: pinning these
// was worth 82->67.6 us). O0..O3 are st64 offsets for rows g*4+0..3.
#define FILLA(S, O0,O1,O2,O3) do{ \
  asm volatile("ds_read2st64_b32 %0, %1 offset0:" #O0 " offset1:" #O1 : "=v"(S##B2[0]) : "v"(aB)); \
  asm volatile("ds_read2st64_b32 %0, %1 offset0:" #O2 " offset1:" #O3 : "=v"(S##B2[1]) : "v"(aB)); \
  asm volatile("ds_read2st64_b32 %0, %1 offset0:" #O0 " offset1:" #O1 : "=v"(S##A2[0]) : "v"(aA)); \
  asm volatile("ds_read2st64_b32 %0, %1 offset0:" #O2 " offset1:" #O3 : "=v"(S##A2[1]) : "v"(aA)); \
  asm volatile("ds_read2st64_b32 %0, %1 offset0:" #O0 " offset1:" #O1 : "=v"(S##C2[0]) : "v"(aC)); \
  asm volatile("ds_read2st64_b32 %0, %1 offset0:" #O2 " offset1:" #O3 : "=v"(S##C2[1]) : "v"(aC)); \
}while(0)

// 4 steps consuming bank S (pairs: S?2[r>>1][r&1] = row g*4+r), then boundary.
// freeze is only true for the single partial chunk (Tn wave-uniform) — all
// full chunks run with zero per-step predication.
#define GROUP(S, gg) do{ _Pragma("unroll") \
    for (int r_ = 0; r_ < 4; ++r_){ \
        const bool commit_ = !freeze || ((k*32 + (gg)*4 + r_) < Tn); \
        step1(S##B2[r_>>1][r_&1], S##A2[r_>>1][r_&1], S##C2[r_>>1][r_&1], commit_); \
        if (r_ < 3) shm3 = shup1(m3); } \
    boundary(early); }while(0)

// One wave per batch. Lane l owns extended states 4l..4l+3 (lane 63 also 256).
// alpha = m * 2^e, exact pow2 rescale every 4 steps (r6-validated math).
// e is INT (integer-valued exponent): f0 = 2^d built by bit-construction,
// bit-identical to fexp2 of an integral arg, but no cvt/trans on the chain.
__global__ __launch_bounds__(64,1)
void ctc_fwd_kernel(const int* __restrict__ y_true,
                    const float* __restrict__ y_pred,
                    const int* __restrict__ input_len,
                    const int* __restrict__ label_len,
                    float* __restrict__ out)
{
    __shared__ float buf[2][32 * NC];   // 2 x 16 KB double-buffered prob rows
    __shared__ float lg_alpha[NS + 3];

    const int b    = blockIdx.x;
    const int lane = threadIdx.x;
    const float* __restrict__ base = y_pred + (size_t)b * NT * NC;

    int Tn = input_len[b];
    Tn = Tn < 0 ? 0 : (Tn > NT ? NT : Tn);   // setup guarantees Tn in [512,1024]

    const int* __restrict__ yrow = y_true + b * NL;
    const int y0v = yrow[2 * lane]     & (NC - 1);   // label for state 4l+1
    const int y1v = yrow[2 * lane + 1] & (NC - 1);   // label for state 4l+3
    const int yp  = shup1i(y1v);                     // y[2l-1] (lane0: unused)
    const bool skip1 = (lane > 0) && (y0v != yp);
    const bool skip3 = (y1v != y0v);
    const bool isl0  = (lane == 0);
    const bool isl63 = (lane == 63);

    float m0 = isl0 ? 1.f : 0.f, m1 = 0.f, m2 = 0.f, m3 = 0.f, m4 = 0.f;
    int   ei  = 0;                // per-lane log2 scale (exact integer)
    float f0  = isl0 ? 0.f : 1.f; // neighbor->self scale factor (per group)
    float fs1 = skip1 ? f0 : 0.f;
    float shm3 = 0.f;             // neighbor's m3 (prev step), own scale

    // three rotating register banks: one 4-step group of p-value pairs each
    v2f s0B2[2], s0A2[2], s0C2[2];
    v2f s1B2[2], s1A2[2], s1C2[2];
    v2f s2B2[2], s2A2[2], s2C2[2];

    auto dma_chunk = [&](int c){              // stage chunk c into buf[c&1]
        const float* gsrc = base + (size_t)c * 32 * NC;
        float* dst = &buf[c & 1][0];
        #pragma unroll
        for (int i = 0; i < 16; ++i)
            dma16(gsrc + i * 256 + lane * 4, dst + i * 256);
    };

    auto step1 = [&](float Pb, float Pa, float Pc, bool commit){
        Pb += EPSF; Pa += EPSF; Pc += EPSF;
        float t3  = skip3 ? m1 : 0.f;
        float n3  = Pc * ((m3 + m2) + t3);
        float n2  = Pb * (m2 + m1);
        float n4  = Pb * (m4 + m3);
        float pm1 = shm3 * f0;                 // alpha[4l-1] in own scale
        float t1  = shm3 * fs1;
        float n0  = Pb * (m0 + pm1);
        float n1  = Pa * ((m1 + m0) + t1);
        if (commit) { m0 = n0; m1 = n1; m2 = n2; m3 = n3; m4 = n4; }
    };

    auto boundary = [&](bool early){
        float mx = fmaxf(fmaxf(m0, m1), fmaxf(m2, m3));
        if (isl63) mx = fmaxf(mx, m4);
        const uint32_t bx = __float_as_uint(mx);
        const int eb = (int)(bx >> 23);
        const float inv = __uint_as_float((uint32_t)(254 - eb) << 23); // exact 2^-ef
        const int de = eb - 127;
        const bool dead = (mx == 0.f);
        int s_nb;
        if (early) {
            // two-pass scale adoption while the reachability front propagates
            int e1 = dead ? ei : (ei + de);
            int s1 = shup1i(e1);
            int e2 = (dead && !isl0) ? s1 : e1;
            int s2 = shup1i(e2);
            ei = (dead && !isl0) ? s2 : e2;
            s_nb = s2;
        } else {
            ei = dead ? ei : (ei + de);
            s_nb = shup1i(ei);
        }
        int d = s_nb - ei;
        d = d < -126 ? -126 : (d > 126 ? 126 : d);
        // 2^d, d integer in [-126,126]: exact bit construction (== fexp2(d))
        f0 = isl0 ? 0.f : __uint_as_float((uint32_t)(d + 127) << 23);
        fs1 = skip1 ? f0 : 0.f;
        m0 *= inv; m1 *= inv; m2 *= inv; m3 *= inv; m4 *= inv;
        shm3 = shup1(m3);                      // post-rescale, matches new f0
    };

    auto chunkbody = [&](int k, bool early, bool freeze){
        const int h = k & 1;
        const unsigned aB = AS3U(&buf[h][NC - 1]);   // blank prob (uniform addr)
        const unsigned aA = AS3U(&buf[h][y0v]);      // label prob, state 4l+1
        const unsigned aC = AS3U(&buf[h][y1v]);      // label prob, state 4l+3

        FILLA(s0,  0, 2, 4, 6);           // group 0 (chunk k already drained)
        if (k + 1 < 32) dma_chunk(k + 1); // stage next chunk (other half)
        FILLA(s1,  8,10,12,14);           // group 1 — 2-deep from the start

        // steady state: every use waits only past the 2 newer in-flight fills
        FILLA(s2, 16,18,20,22); WAITLGKM(12); GROUP(s0, 0);
        FILLA(s0, 24,26,28,30); WAITLGKM(12); GROUP(s1, 1);
        FILLA(s1, 32,34,36,38); WAITLGKM(12); GROUP(s2, 2);
        FILLA(s2, 40,42,44,46); WAITLGKM(12); GROUP(s0, 3);
        FILLA(s0, 48,50,52,54); WAITLGKM(12); GROUP(s1, 4);
        FILLA(s1, 56,58,60,62); WAITLGKM(12); GROUP(s2, 5);
                                WAITLGKM(6);  GROUP(s0, 6);
                                WAITLGKM(0);  GROUP(s1, 7);

        VM_DRAIN();   // next chunk's DMA complete; barrier for the compiler too
    };

    // prologue: stage chunk 0, drain
    dma_chunk(0);
    VM_DRAIN();

    // Tn in [512,1024] wave-uniform. Chunks < nfull are fully active (no
    // per-step predication); at most ONE partial chunk keeps the cndmask
    // path; chunks past Tn are exact no-ops (post-rescale max is in [1,2) so
    // inv=1, ef=0, f0/fs1/shm3 recompute identically) -> skip them, bit-exact.
    const int nfull = Tn >> 5;                // >= 16
    #pragma unroll 1
    for (int k = 0; k < 8; ++k)       chunkbody(k, true,  false);
    #pragma unroll 1
    for (int k = 8; k < nfull; ++k)   chunkbody(k, false, false);
    if (nfull < 32 && (Tn & 31))      chunkbody(nfull, false, true);

    // ---- epilogue ----
    const float e = (float)ei;                // exact int->float
    lg_alpha[4 * lane + 0] = (m0 > 0.f) ? (e + flog2(m0)) : NEGL2;
    lg_alpha[4 * lane + 1] = (m1 > 0.f) ? (e + flog2(m1)) : NEGL2;
    lg_alpha[4 * lane + 2] = (m2 > 0.f) ? (e + flog2(m2)) : NEGL2;
    lg_alpha[4 * lane + 3] = (m3 > 0.f) ? (e + flog2(m3)) : NEGL2;
    if (isl63) lg_alpha[256] = (m4 > 0.f) ? (e + flog2(m4)) : NEGL2;
    __syncthreads();

    if (lane == 0) {
        int lab = label_len[b];
        lab = lab < 0 ? 0 : (lab > NL ? NL : lab);
        const int i_last = 2 * lab;
        const int i_prev = i_last > 0 ? i_last - 1 : 0;
        float A  = lg_alpha[i_last];
        float Bv = lg_alpha[i_prev];
        float mx = fmaxf(A, Bv);
        float r;
        if (mx < -1.0e29f) {
            r = mx;
        } else {
            float s = fexp2(A - mx) + fexp2(Bv - mx);
            r = mx + flog2(s);
        }
        out[b] = -r * LN2F;
    }
}

extern "C" void kernel_launch(void* const* d_in, const int* in_sizes, int n_in,
                              void* d_out, int out_size, void* d_ws, size_t ws_size,
                              hipStream_t stream) {
    const int*   y_true    = (const int*)d_in[0];
    const float* y_pred    = (const float*)d_in[1];
    const int*   input_len = (const int*)d_in[2];
    const int*   label_len = (const int*)d_in[3];
    float* outp = (float*)d_out;
    ctc_fwd_kernel<<<dim3(NB), dim3(64), 0, stream>>>(y_true, y_pred, input_len, label_len, outp);
}

// Round 7
// 134.954 us; speedup vs baseline: 1.5272x; 1.0749x over previous
//
#include <hip/hip_runtime.h>
#include <cstdint>

#define NB 128
#define NT 1024
#define NC 128
#define NL 128
#define NS 257
#define EPSF 1e-7f
#define LN2F 0.69314718055994530942f
#define NEGL2 -1.442695e30f   // *ln2 ~= -1e30 (reference NEG)

typedef float __attribute__((ext_vector_type(2))) v2f;

__device__ __forceinline__ float fexp2(float x){ return __builtin_amdgcn_exp2f(x); }
__device__ __forceinline__ float flog2(float x){ return __builtin_amdgcn_logf(x); }

// Wave shift-up-by-1 in the VALU pipe: v_mov_b32_dpp wave_shr:1 (ctrl 0x138),
// bound_ctrl=1 -> lane 0 receives 0. All call sites are lane-0-safe.
__device__ __forceinline__ float shup1(float x){
    int r = __builtin_amdgcn_update_dpp(0, __float_as_int(x), 0x138, 0xf, 0xf, true);
    return __int_as_float(r);
}
__device__ __forceinline__ int shup1i(int x){
    return __builtin_amdgcn_update_dpp(0, x, 0x138, 0xf, 0xf, true);
}

// Async global->LDS DMA, 16 B/lane, wave-uniform LDS base (HW adds lane*16).
// Tracked by vmcnt; zero registers; issue cost only — off the serial chain.
__device__ __forceinline__ void dma16(const float* g, float* lds){
    __builtin_amdgcn_global_load_lds((const __attribute__((address_space(1))) void*)g,
                                     (__attribute__((address_space(3))) void*)lds,
                                     16, 0, 0);
}

// HW drain of DMA + compiler-level memory barrier (no load may cross).
#define VM_DRAIN() asm volatile("s_waitcnt vmcnt(0)" ::: "memory")

// LDS byte-offset of a __shared__ address (for raw ds_read asm).
#define AS3U(p) ((unsigned)(size_t)(__attribute__((address_space(3))) void*)(p))

// Hand-counted LDS wait + scheduling wall (rule #18: the sched_barrier stops
// the compiler hoisting dependent VALU between the ds_read asm and the wait).
#define WAITLGKM(N) do{ asm volatile("s_waitcnt lgkmcnt(" #N ")" ::: "memory"); \
                        __builtin_amdgcn_sched_barrier(0); }while(0)

// Pinned fill: 6x volatile ds_read2st64_b32 (st64 unit = 256 B; row stride
// 512 B = 2 units). Volatile asm cannot be reordered against other volatile
// asm, so these ISSUE here — two groups ahead of their consumer — and cannot
// be sunk to just-before-use by the scheduler (r5-confirmed: pinning these
// was worth 82->67.6 us). O0..O3 are st64 offsets for rows g*4+0..3.
#define FILLA(S, O0,O1,O2,O3) do{ \
  asm volatile("ds_read2st64_b32 %0, %1 offset0:" #O0 " offset1:" #O1 : "=v"(S##B2[0]) : "v"(aB)); \
  asm volatile("ds_read2st64_b32 %0, %1 offset0:" #O2 " offset1:" #O3 : "=v"(S##B2[1]) : "v"(aB)); \
  asm volatile("ds_read2st64_b32 %0, %1 offset0:" #O0 " offset1:" #O1 : "=v"(S##A2[0]) : "v"(aA)); \
  asm volatile("ds_read2st64_b32 %0, %1 offset0:" #O2 " offset1:" #O3 : "=v"(S##A2[1]) : "v"(aA)); \
  asm volatile("ds_read2st64_b32 %0, %1 offset0:" #O0 " offset1:" #O1 : "=v"(S##C2[0]) : "v"(aC)); \
  asm volatile("ds_read2st64_b32 %0, %1 offset0:" #O2 " offset1:" #O3 : "=v"(S##C2[1]) : "v"(aC)); \
}while(0)

// 4 steps consuming bank S. EPS is applied as PACKED v2f adds on the fill
// pairs (v_pk_add_f32: 3 instr per 2 steps instead of 3 per step, IEEE-
// identical per half). freeze only for the single partial chunk.
#define GROUP(S, gg) do{ \
    const v2f pb0 = S##B2[0] + E2, pa0 = S##A2[0] + E2, pc0 = S##C2[0] + E2; \
    const v2f pb1 = S##B2[1] + E2, pa1 = S##A2[1] + E2, pc1 = S##C2[1] + E2; \
    { const bool c_ = !freeze || ((k*32 + (gg)*4 + 0) < Tn); step1(pb0.x, pa0.x, pc0.x, c_); } \
    shm3 = shup1(m3); \
    { const bool c_ = !freeze || ((k*32 + (gg)*4 + 1) < Tn); step1(pb0.y, pa0.y, pc0.y, c_); } \
    shm3 = shup1(m3); \
    { const bool c_ = !freeze || ((k*32 + (gg)*4 + 2) < Tn); step1(pb1.x, pa1.x, pc1.x, c_); } \
    shm3 = shup1(m3); \
    { const bool c_ = !freeze || ((k*32 + (gg)*4 + 3) < Tn); step1(pb1.y, pa1.y, pc1.y, c_); } \
    boundary(early); }while(0)

// One wave per batch. Lane l owns extended states 4l..4l+3 (lane 63 also 256).
// alpha = m * 2^e, exact pow2 rescale every 4 steps (r6-validated math).
// e is INT; f0 = 2^d bit-constructed (bit-identical to fexp2 of integral arg).
__global__ __launch_bounds__(64,1)
void ctc_fwd_kernel(const int* __restrict__ y_true,
                    const float* __restrict__ y_pred,
                    const int* __restrict__ input_len,
                    const int* __restrict__ label_len,
                    float* __restrict__ out)
{
    __shared__ float buf[2][32 * NC];   // 2 x 16 KB double-buffered prob rows
    __shared__ float lg_alpha[NS + 3];

    const int b    = blockIdx.x;
    const int lane = threadIdx.x;
    const float* __restrict__ base = y_pred + (size_t)b * NT * NC;

    int Tn = input_len[b];
    Tn = Tn < 0 ? 0 : (Tn > NT ? NT : Tn);   // setup guarantees Tn in [512,1024]

    const int* __restrict__ yrow = y_true + b * NL;
    const int y0v = yrow[2 * lane]     & (NC - 1);   // label for state 4l+1
    const int y1v = yrow[2 * lane + 1] & (NC - 1);   // label for state 4l+3
    const int yp  = shup1i(y1v);                     // y[2l-1] (lane0: unused)
    const bool skip1 = (lane > 0) && (y0v != yp);
    const bool skip3 = (y1v != y0v);
    const bool isl0  = (lane == 0);
    const bool isl63 = (lane == 63);
    const float skip3f = skip3 ? 1.f : 0.f;  // exact {0,1} multiplier for t3

    const v2f E2 = { EPSF, EPSF };

    float m0 = isl0 ? 1.f : 0.f, m1 = 0.f, m2 = 0.f, m3 = 0.f, m4 = 0.f;
    int   ei  = 0;                // per-lane log2 scale (exact integer)
    float f0  = isl0 ? 0.f : 1.f; // neighbor->self scale factor (per group)
    float fs1 = skip1 ? f0 : 0.f;
    float shm3 = 0.f;             // neighbor's m3 (prev step), own scale

    // three rotating register banks: one 4-step group of p-value pairs each
    v2f s0B2[2], s0A2[2], s0C2[2];
    v2f s1B2[2], s1A2[2], s1C2[2];
    v2f s2B2[2], s2A2[2], s2C2[2];

    auto dma_chunk = [&](int c){              // stage chunk c into buf[c&1]
        const float* gsrc = base + (size_t)c * 32 * NC;
        float* dst = &buf[c & 1][0];
        #pragma unroll
        for (int i = 0; i < 16; ++i)
            dma16(gsrc + i * 256 + lane * 4, dst + i * 256);
    };

    // Per-step transition. fmaf choices are bit-safe:
    //  a6: product m1*skip3f is EXACT ({0,1} multiplier) -> fma == cnd+add.
    //  a7/a4: single-use mul+add chains the compiler already contracts under
    //  -ffp-contract=fast; written explicitly to drop the separate muls.
    auto step1 = [&](float Pb, float Pa, float Pc, bool commit){
        float a1  = m3 + m2;
        float a2  = m2 + m1;
        float s43 = m4 + m3;
        float a5  = m1 + m0;
        float a6  = fmaf(m1,   skip3f, a1);   // a1 + (skip3 ? m1 : 0)
        float a7  = fmaf(shm3, fs1,    a5);   // a5 + shm3*fs1
        float a4  = fmaf(shm3, f0,     m0);   // m0 + shm3*f0
        float n3 = Pc * a6;
        float n2 = Pb * a2;
        float n4 = Pb * s43;
        float n0 = Pb * a4;
        float n1 = Pa * a7;
        if (commit) { m0 = n0; m1 = n1; m2 = n2; m3 = n3; m4 = n4; }
    };

    auto boundary = [&](bool early){
        float mx = fmaxf(fmaxf(m0, m1), fmaxf(m2, m3));
        if (isl63) mx = fmaxf(mx, m4);
        const uint32_t bx = __float_as_uint(mx);
        const int eb = (int)(bx >> 23);
        const float inv = __uint_as_float((uint32_t)(254 - eb) << 23); // exact 2^-ef
        const int de = eb - 127;
        const bool dead = (mx == 0.f);
        int s_nb;
        if (early) {
            // two-pass scale adoption while the reachability front propagates
            int e1 = dead ? ei : (ei + de);
            int s1 = shup1i(e1);
            int e2 = (dead && !isl0) ? s1 : e1;
            int s2 = shup1i(e2);
            ei = (dead && !isl0) ? s2 : e2;
            s_nb = s2;
        } else {
            ei = dead ? ei : (ei + de);
            s_nb = shup1i(ei);
        }
        int d = s_nb - ei;
        d = d < -126 ? -126 : (d > 126 ? 126 : d);
        // 2^d, d integer in [-126,126]: exact bit construction (== fexp2(d))
        f0 = isl0 ? 0.f : __uint_as_float((uint32_t)(d + 127) << 23);
        fs1 = skip1 ? f0 : 0.f;
        m0 *= inv; m1 *= inv; m2 *= inv; m3 *= inv; m4 *= inv;
        shm3 = shup1(m3);                      // post-rescale, matches new f0
    };

    auto chunkbody = [&](int k, bool early, bool freeze){
        const int h = k & 1;
        const unsigned aB = AS3U(&buf[h][NC - 1]);   // blank prob (uniform addr)
        const unsigned aA = AS3U(&buf[h][y0v]);      // label prob, state 4l+1
        const unsigned aC = AS3U(&buf[h][y1v]);      // label prob, state 4l+3

        FILLA(s0,  0, 2, 4, 6);           // group 0 (chunk k already drained)
        if (k + 1 < 32) dma_chunk(k + 1); // stage next chunk (other half)
        FILLA(s1,  8,10,12,14);           // group 1 — 2-deep from the start

        // steady state: every use waits only past the 2 newer in-flight fills
        FILLA(s2, 16,18,20,22); WAITLGKM(12); GROUP(s0, 0);
        FILLA(s0, 24,26,28,30); WAITLGKM(12); GROUP(s1, 1);
        FILLA(s1, 32,34,36,38); WAITLGKM(12); GROUP(s2, 2);
        FILLA(s2, 40,42,44,46); WAITLGKM(12); GROUP(s0, 3);
        FILLA(s0, 48,50,52,54); WAITLGKM(12); GROUP(s1, 4);
        FILLA(s1, 56,58,60,62); WAITLGKM(12); GROUP(s2, 5);
                                WAITLGKM(6);  GROUP(s0, 6);
                                WAITLGKM(0);  GROUP(s1, 7);

        VM_DRAIN();   // next chunk's DMA complete; barrier for the compiler too
    };

    // prologue: stage chunk 0, drain
    dma_chunk(0);
    VM_DRAIN();

    // Tn in [512,1024] wave-uniform. Chunks < nfull are fully active (no
    // per-step predication); at most ONE partial chunk keeps the cndmask
    // path; chunks past Tn are exact no-ops (post-rescale max is in [1,2) so
    // inv=1, ef=0, f0/fs1/shm3 recompute identically) -> skip them, bit-exact.
    const int nfull = Tn >> 5;                // >= 16
    #pragma unroll 1
    for (int k = 0; k < 8; ++k)       chunkbody(k, true,  false);
    #pragma unroll 1
    for (int k = 8; k < nfull; ++k)   chunkbody(k, false, false);
    if (nfull < 32 && (Tn & 31))      chunkbody(nfull, false, true);

    // ---- epilogue ----
    const float e = (float)ei;                // exact int->float
    lg_alpha[4 * lane + 0] = (m0 > 0.f) ? (e + flog2(m0)) : NEGL2;
    lg_alpha[4 * lane + 1] = (m1 > 0.f) ? (e + flog2(m1)) : NEGL2;
    lg_alpha[4 * lane + 2] = (m2 > 0.f) ? (e + flog2(m2)) : NEGL2;
    lg_alpha[4 * lane + 3] = (m3 > 0.f) ? (e + flog2(m3)) : NEGL2;
    if (isl63) lg_alpha[256] = (m4 > 0.f) ? (e + flog2(m4)) : NEGL2;
    __syncthreads();

    if (lane == 0) {
        int lab = label_len[b];
        lab = lab < 0 ? 0 : (lab > NL ? NL : lab);
        const int i_last = 2 * lab;
        const int i_prev = i_last > 0 ? i_last - 1 : 0;
        float A  = lg_alpha[i_last];
        float Bv = lg_alpha[i_prev];
        float mx = fmaxf(A, Bv);
        float r;
        if (mx < -1.0e29f) {
            r = mx;
        } else {
            float s = fexp2(A - mx) + fexp2(Bv - mx);
            r = mx + flog2(s);
        }
        out[b] = -r * LN2F;
    }
}

extern "C" void kernel_launch(void* const* d_in, const int* in_sizes, int n_in,
                              void* d_out, int out_size, void* d_ws, size_t ws_size,
                              hipStream_t stream) {
    const int*   y_true    = (const int*)d_in[0];
    const float* y_pred    = (const float*)d_in[1];
    const int*   input_len = (const int*)d_in[2];
    const int*   label_len = (const int*)d_in[3];
    float* outp = (float*)d_out;
    ctc_fwd_kernel<<<dim3(NB), dim3(64), 0, stream>>>(y_true, y_pred, input_len, label_len, outp);
}

// Round 8
// 131.677 us; speedup vs baseline: 1.5652x; 1.0249x over previous
//
#include <hip/hip_runtime.h>
#include <cstdint>

#define NB 128
#define NT 1024
#define NC 128
#define NL 128
#define NS 257
#define EPSF 1e-7f
#define LN2F 0.69314718055994530942f
#define NEGL2 -1.442695e30f   // *ln2 ~= -1e30 (reference NEG)

typedef float __attribute__((ext_vector_type(2))) v2f;

__device__ __forceinline__ float fexp2(float x){ return __builtin_amdgcn_exp2f(x); }
__device__ __forceinline__ float flog2(float x){ return __builtin_amdgcn_logf(x); }

// Wave shift-up-by-1 in the VALU pipe: v_mov_b32_dpp wave_shr:1 (ctrl 0x138),
// bound_ctrl=1 -> lane 0 receives 0. All call sites are lane-0-safe.
__device__ __forceinline__ float shup1(float x){
    int r = __builtin_amdgcn_update_dpp(0, __float_as_int(x), 0x138, 0xf, 0xf, true);
    return __int_as_float(r);
}
__device__ __forceinline__ int shup1i(int x){
    return __builtin_amdgcn_update_dpp(0, x, 0x138, 0xf, 0xf, true);
}

// Full-rate packed f32 (VOP3P, CDNA since MI100). Each half is an IEEE f32
// op -> bit-identical to the scalar pair it replaces. One instr for two.
__device__ __forceinline__ v2f pk_add(v2f a, v2f b){
    v2f r; asm("v_pk_add_f32 %0, %1, %2" : "=v"(r) : "v"(a), "v"(b)); return r;
}
__device__ __forceinline__ v2f pk_mul(v2f a, v2f b){
    v2f r; asm("v_pk_mul_f32 %0, %1, %2" : "=v"(r) : "v"(a), "v"(b)); return r;
}
// Broadcast one 32-bit word of src0 to both halves via op_sel (no mov):
// blo: (a.lo*b.lo, a.lo*b.hi)   bhi: (a.hi*b.lo, a.hi*b.hi)
__device__ __forceinline__ v2f pk_mul_blo(v2f a, v2f b){
    v2f r; asm("v_pk_mul_f32 %0, %1, %2 op_sel:[0,0] op_sel_hi:[0,1]"
               : "=v"(r) : "v"(a), "v"(b)); return r;
}
__device__ __forceinline__ v2f pk_mul_bhi(v2f a, v2f b){
    v2f r; asm("v_pk_mul_f32 %0, %1, %2 op_sel:[1,0] op_sel_hi:[1,1]"
               : "=v"(r) : "v"(a), "v"(b)); return r;
}
__device__ __forceinline__ float max3f(float a, float b, float c){
    float r; asm("v_max3_f32 %0, %1, %2, %3" : "=v"(r) : "v"(a), "v"(b), "v"(c));
    return r;
}

// Async global->LDS DMA, 16 B/lane, wave-uniform LDS base (HW adds lane*16).
// Tracked by vmcnt; zero registers; issue cost only — off the serial chain.
__device__ __forceinline__ void dma16(const float* g, float* lds){
    __builtin_amdgcn_global_load_lds((const __attribute__((address_space(1))) void*)g,
                                     (__attribute__((address_space(3))) void*)lds,
                                     16, 0, 0);
}

// HW drain of DMA + compiler-level memory barrier (no load may cross).
#define VM_DRAIN() asm volatile("s_waitcnt vmcnt(0)" ::: "memory")

// LDS byte-offset of a __shared__ address (for raw ds_read asm).
#define AS3U(p) ((unsigned)(size_t)(__attribute__((address_space(3))) void*)(p))

// Hand-counted LDS wait + scheduling wall (rule #18: the sched_barrier stops
// the compiler hoisting dependent VALU between the ds_read asm and the wait).
#define WAITLGKM(N) do{ asm volatile("s_waitcnt lgkmcnt(" #N ")" ::: "memory"); \
                        __builtin_amdgcn_sched_barrier(0); }while(0)

// Pinned fill: 6x volatile ds_read2st64_b32 (st64 unit = 256 B; row stride
// 512 B = 2 units). Volatile asm cannot be reordered against other volatile
// asm, so these ISSUE here — two groups ahead of their consumer — and cannot
// be sunk to just-before-use by the scheduler (r5-confirmed: pinning these
// was worth 82->67.6 us). O0..O3 are st64 offsets for rows g*4+0..3.
#define FILLA(S, O0,O1,O2,O3) do{ \
  asm volatile("ds_read2st64_b32 %0, %1 offset0:" #O0 " offset1:" #O1 : "=v"(S##B2[0]) : "v"(aB)); \
  asm volatile("ds_read2st64_b32 %0, %1 offset0:" #O2 " offset1:" #O3 : "=v"(S##B2[1]) : "v"(aB)); \
  asm volatile("ds_read2st64_b32 %0, %1 offset0:" #O0 " offset1:" #O1 : "=v"(S##A2[0]) : "v"(aA)); \
  asm volatile("ds_read2st64_b32 %0, %1 offset0:" #O2 " offset1:" #O3 : "=v"(S##A2[1]) : "v"(aA)); \
  asm volatile("ds_read2st64_b32 %0, %1 offset0:" #O0 " offset1:" #O1 : "=v"(S##C2[0]) : "v"(aC)); \
  asm volatile("ds_read2st64_b32 %0, %1 offset0:" #O2 " offset1:" #O3 : "=v"(S##C2[1]) : "v"(aC)); \
}while(0)

// 4 steps consuming bank S. EPS applied as packed adds on the fill pairs
// (pk_add asm: guaranteed 1 instr per pair). freeze only in the partial chunk.
#define GROUP(S, gg) do{ \
    const v2f pb0 = pk_add(S##B2[0], E2), pa0 = pk_add(S##A2[0], E2), pc0 = pk_add(S##C2[0], E2); \
    const v2f pb1 = pk_add(S##B2[1], E2), pa1 = pk_add(S##A2[1], E2), pc1 = pk_add(S##C2[1], E2); \
    { const bool c_ = !freeze || ((k*32 + (gg)*4 + 0) < Tn); step1(pb0, pa0, pc0, false, c_); } \
    shm3 = shup1(P13.y); \
    { const bool c_ = !freeze || ((k*32 + (gg)*4 + 1) < Tn); step1(pb0, pa0, pc0, true,  c_); } \
    shm3 = shup1(P13.y); \
    { const bool c_ = !freeze || ((k*32 + (gg)*4 + 2) < Tn); step1(pb1, pa1, pc1, false, c_); } \
    shm3 = shup1(P13.y); \
    { const bool c_ = !freeze || ((k*32 + (gg)*4 + 3) < Tn); step1(pb1, pa1, pc1, true,  c_); } \
    boundary(early); }while(0)

// One wave per batch. Lane l owns extended states 4l..4l+3 (lane 63 also 256).
// alpha = m * 2^e, exact pow2 rescale every 4 steps (r6-validated math).
// State lives as packed pairs P13=(m1,m3), P24=(m2,m4) + scalar m0 so the
// recurrence's natural pairs run on v_pk_*_f32 (r7 slope: ~5.5 cyc per
// removed instruction — instruction count IS the wall clock here).
__global__ __launch_bounds__(64,1)
void ctc_fwd_kernel(const int* __restrict__ y_true,
                    const float* __restrict__ y_pred,
                    const int* __restrict__ input_len,
                    const int* __restrict__ label_len,
                    float* __restrict__ out)
{
    __shared__ float buf[2][32 * NC];   // 2 x 16 KB double-buffered prob rows
    __shared__ float lg_alpha[NS + 3];

    const int b    = blockIdx.x;
    const int lane = threadIdx.x;
    const float* __restrict__ base = y_pred + (size_t)b * NT * NC;

    int Tn = input_len[b];
    Tn = Tn < 0 ? 0 : (Tn > NT ? NT : Tn);   // setup guarantees Tn in [512,1024]

    const int* __restrict__ yrow = y_true + b * NL;
    const int y0v = yrow[2 * lane]     & (NC - 1);   // label for state 4l+1
    const int y1v = yrow[2 * lane + 1] & (NC - 1);   // label for state 4l+3
    const int yp  = shup1i(y1v);                     // y[2l-1] (lane0: unused)
    const bool skip1 = (lane > 0) && (y0v != yp);
    const bool skip3 = (y1v != y0v);
    const bool isl0  = (lane == 0);
    const bool isl63 = (lane == 63);
    const float skip3f = skip3 ? 1.f : 0.f;  // exact {0,1} multiplier for t3

    const v2f E2 = { EPSF, EPSF };

    float m0 = isl0 ? 1.f : 0.f;
    v2f P13 = { 0.f, 0.f };       // (m1, m3)
    v2f P24 = { 0.f, 0.f };       // (m2, m4)
    int   ei  = 0;                // per-lane log2 scale (exact integer)
    float f0  = isl0 ? 0.f : 1.f; // neighbor->self scale factor (per group)
    float fs1 = skip1 ? f0 : 0.f;
    float shm3 = 0.f;             // neighbor's m3 (prev step), own scale

    // three rotating register banks: one 4-step group of p-value pairs each
    v2f s0B2[2], s0A2[2], s0C2[2];
    v2f s1B2[2], s1A2[2], s1C2[2];
    v2f s2B2[2], s2A2[2], s2C2[2];

    auto dma_chunk = [&](int c){              // stage chunk c into buf[c&1]
        const float* gsrc = base + (size_t)c * 32 * NC;
        float* dst = &buf[c & 1][0];
        #pragma unroll
        for (int i = 0; i < 16; ++i)
            dma16(gsrc + i * 256 + lane * 4, dst + i * 256);
    };

    // Per-step transition (bit-exact to r7's scalar form):
    //  S = (m2+m1, m4+m3) in one pk_add; (n2,n4) in one pk_mul with the
    //  needed Pb half broadcast straight from the fill pair (op_sel, no mov).
    //  fmas as in r7 (a6's {0,1} multiplier is exact; a7/a4 contracted).
    auto step1 = [&](v2f pb, v2f pa, v2f pc, bool hi, bool commit){
        const float Pb = hi ? pb.y : pb.x;
        const float Pa = hi ? pa.y : pa.x;
        const float Pc = hi ? pc.y : pc.x;
        v2f S = pk_add(P24, P13);                 // (a2, s43)
        float a1 = P13.y + P24.x;                 // m3+m2
        float D  = P13.x + m0;                    // m1+m0
        float a6 = fmaf(P13.x, skip3f, a1);
        float a7 = fmaf(shm3, fs1, D);
        float a4 = fmaf(shm3, f0, m0);
        v2f nP24 = hi ? pk_mul_bhi(pb, S) : pk_mul_blo(pb, S);   // (n2, n4)
        float n0 = Pb * a4;
        float n1 = Pa * a7;
        float n3 = Pc * a6;
        if (commit){ m0 = n0; P13.x = n1; P13.y = n3; P24 = nP24; }
    };

    auto boundary = [&](bool early){
        float mx = max3f(m0, P13.x, P13.y);
        mx = fmaxf(mx, P24.x);
        if (isl63) mx = fmaxf(mx, P24.y);
        const uint32_t bx = __float_as_uint(mx);
        const int eb = (int)(bx >> 23);
        const float inv = __uint_as_float((uint32_t)(254 - eb) << 23); // exact 2^-ef
        const int de = eb - 127;
        int s_nb;
        if (early) {
            // two-pass scale adoption while the reachability front propagates
            const bool dead = (mx == 0.f);
            int e1 = dead ? ei : (ei + de);
            int s1 = shup1i(e1);
            int e2 = (dead && !isl0) ? s1 : e1;
            int s2 = shup1i(e2);
            ei = (dead && !isl0) ? s2 : e2;
            s_nb = s2;
        } else {
            // k>=8 (t>=256): front has covered all 257 states and p>=EPS>0
            // keeps every reached m strictly positive -> no dead lanes.
            ei += de;
            s_nb = shup1i(ei);
        }
        int d = s_nb - ei;
        d = d < -126 ? -126 : (d > 126 ? 126 : d);
        // 2^d, d integer in [-126,126]: exact bit construction (== fexp2(d))
        f0 = isl0 ? 0.f : __uint_as_float((uint32_t)(d + 127) << 23);
        fs1 = skip1 ? f0 : 0.f;
        const v2f inv2 = { inv, inv };
        P13 = pk_mul(inv2, P13);              // exact pow2 rescale
        P24 = pk_mul(inv2, P24);
        m0 *= inv;
        shm3 = shup1(P13.y);                  // post-rescale, matches new f0
    };

    auto chunkbody = [&](int k, bool early, bool freeze){
        const int h = k & 1;
        const unsigned aB = AS3U(&buf[h][NC - 1]);   // blank prob (uniform addr)
        const unsigned aA = AS3U(&buf[h][y0v]);      // label prob, state 4l+1
        const unsigned aC = AS3U(&buf[h][y1v]);      // label prob, state 4l+3

        FILLA(s0,  0, 2, 4, 6);           // group 0 (chunk k already drained)
        if (k + 1 < 32) dma_chunk(k + 1); // stage next chunk (other half)
        FILLA(s1,  8,10,12,14);           // group 1 — 2-deep from the start

        // steady state: every use waits only past the 2 newer in-flight fills
        FILLA(s2, 16,18,20,22); WAITLGKM(12); GROUP(s0, 0);
        FILLA(s0, 24,26,28,30); WAITLGKM(12); GROUP(s1, 1);
        FILLA(s1, 32,34,36,38); WAITLGKM(12); GROUP(s2, 2);
        FILLA(s2, 40,42,44,46); WAITLGKM(12); GROUP(s0, 3);
        FILLA(s0, 48,50,52,54); WAITLGKM(12); GROUP(s1, 4);
        FILLA(s1, 56,58,60,62); WAITLGKM(12); GROUP(s2, 5);
                                WAITLGKM(6);  GROUP(s0, 6);
                                WAITLGKM(0);  GROUP(s1, 7);

        VM_DRAIN();   // next chunk's DMA complete; barrier for the compiler too
    };

    // prologue: stage chunk 0, drain
    dma_chunk(0);
    VM_DRAIN();

    // Tn in [512,1024] wave-uniform. Chunks < nfull are fully active (no
    // per-step predication); at most ONE partial chunk keeps the cndmask
    // path; chunks past Tn are exact no-ops (post-rescale max is in [1,2) so
    // inv=1, ef=0, f0/fs1/shm3 recompute identically) -> skip them, bit-exact.
    const int nfull = Tn >> 5;                // >= 16
    #pragma unroll 1
    for (int k = 0; k < 8; ++k)       chunkbody(k, true,  false);
    #pragma unroll 1
    for (int k = 8; k < nfull; ++k)   chunkbody(k, false, false);
    if (nfull < 32 && (Tn & 31))      chunkbody(nfull, false, true);

    // ---- epilogue ----
    const float e = (float)ei;                // exact int->float
    lg_alpha[4 * lane + 0] = (m0    > 0.f) ? (e + flog2(m0))    : NEGL2;
    lg_alpha[4 * lane + 1] = (P13.x > 0.f) ? (e + flog2(P13.x)) : NEGL2;
    lg_alpha[4 * lane + 2] = (P24.x > 0.f) ? (e + flog2(P24.x)) : NEGL2;
    lg_alpha[4 * lane + 3] = (P13.y > 0.f) ? (e + flog2(P13.y)) : NEGL2;
    if (isl63) lg_alpha[256] = (P24.y > 0.f) ? (e + flog2(P24.y)) : NEGL2;
    __syncthreads();

    if (lane == 0) {
        int lab = label_len[b];
        lab = lab < 0 ? 0 : (lab > NL ? NL : lab);
        const int i_last = 2 * lab;
        const int i_prev = i_last > 0 ? i_last - 1 : 0;
        float A  = lg_alpha[i_last];
        float Bv = lg_alpha[i_prev];
        float mx = fmaxf(A, Bv);
        float r;
        if (mx < -1.0e29f) {
            r = mx;
        } else {
            float s = fexp2(A - mx) + fexp2(Bv - mx);
            r = mx + flog2(s);
        }
        out[b] = -r * LN2F;
    }
}

extern "C" void kernel_launch(void* const* d_in, const int* in_sizes, int n_in,
                              void* d_out, int out_size, void* d_ws, size_t ws_size,
                              hipStream_t stream) {
    const int*   y_true    = (const int*)d_in[0];
    const float* y_pred    = (const float*)d_in[1];
    const int*   input_len = (const int*)d_in[2];
    const int*   label_len = (const int*)d_in[3];
    float* outp = (float*)d_out;
    ctc_fwd_kernel<<<dim3(NB), dim3(64), 0, stream>>>(y_true, y_pred, input_len, label_len, outp);
}